// Round 1
// baseline (2788.068 us; speedup 1.0000x reference)
//
#include <hip/hip_runtime.h>
#include <hip/hip_fp16.h>

// ---------------- constants ----------------
#define NN 883            // nodes
#define NP 896            // padded nodes (7*128)
#define DD 64             // rnn units
#define BB 32             // batch
#define BD 2048           // BB*DD (gemm cols)
#define LL 12             // seq len
#define HH 12             // horizon
#define MM 5              // diffusion supports count
#define K2LEN 1792        // 2*NP

typedef _Float16 f16;
typedef _Float16 f16x4 __attribute__((ext_vector_type(4)));
typedef _Float16 f16x8 __attribute__((ext_vector_type(8)));
typedef float    f32x4 __attribute__((ext_vector_type(4)));

// ---------------- prep: row/col sums of adj ----------------
__global__ __launch_bounds__(256) void k_colrow(const float* __restrict__ A,
                                                float* __restrict__ invr,
                                                float* __restrict__ invc) {
  int x = blockIdx.x, tid = threadIdx.x;
  if (x < NN) {
    float s = 0.f;
    for (int i = tid; i < NN; i += 256) s += A[(size_t)x * NN + i];
    __shared__ float red[256];
    red[tid] = s; __syncthreads();
    for (int st = 128; st; st >>= 1) { if (tid < st) red[tid] += red[tid + st]; __syncthreads(); }
    if (tid == 0) invr[x] = 1.0f / red[0];
  } else {
    int m = (x - NN) * 256 + tid;
    if (m < NN) {
      float s = 0.f;
      for (int i = 0; i < NN; i++) s += A[(size_t)i * NN + m];
      invc[m] = 1.0f / s;
    }
  }
}

// S12[m][k]: k<NP -> S1[m][k]=A[k][m]/rowsum[k]; k>=NP -> S2[m][k-NP]=A[m][kk]/colsum[kk]
__global__ __launch_bounds__(256) void k_sfill(const float* __restrict__ A,
                                               const float* __restrict__ invr,
                                               const float* __restrict__ invc,
                                               f16* __restrict__ S12) {
  int m = blockIdx.x;
  int k = blockIdx.y * 256 + threadIdx.x;
  float v = 0.f;
  if (m < NN) {
    if (k < NP) { if (k < NN) v = A[(size_t)k * NN + m] * invr[k]; }
    else { int kk = k - NP; if (kk < NN) v = A[(size_t)m * NN + kk] * invc[kk]; }
  }
  S12[(size_t)m * K2LEN + k] = (f16)v;
}

// W reorg + rank1 vectors + R-dot precompute
__global__ __launch_bounds__(256) void k_wprep(
    const float* __restrict__ egw, const float* __restrict__ dgw,
    const float* __restrict__ emw, const float* __restrict__ emb,
    const float* __restrict__ eR,  const float* __restrict__ dR,
    const float* __restrict__ eaw, const float* __restrict__ daw,
    f16* __restrict__ W2te, f16* __restrict__ W2td,
    float* __restrict__ uv, float* __restrict__ rdot) {
  int bx = blockIdx.x, tid = threadIdx.x;
  if (bx < 12) {
    int ph = bx / 6, k = bx % 6;
    const float* R  = ph ? dR : eR;
    const float* aw = ph ? daw : eaw;
    const float* Rk = R + (size_t)k * NN * DD;
    float s = 0.f;
    for (int i = tid; i < NN * DD; i += 256) s += Rk[i] * aw[i];
    __shared__ float red[256];
    red[tid] = s; __syncthreads();
    for (int st = 128; st; st >>= 1) { if (tid < st) red[tid] += red[tid + st]; __syncthreads(); }
    if (tid == 0) rdot[ph * 6 + k] = red[0];
  } else if (bx == 12) {
    if (tid < 320) {
      int m = tid / 64, d = tid % 64;
      float u = 0.f, v = 0.f;
      for (int f = 0; f < 64; f++) {
        float w = egw[(size_t)(f * MM + m) * DD + d];
        u += emw[f] * w;
        v += emb[f] * w;
      }
      uv[tid] = u; uv[320 + tid] = v;
    }
  } else if (bx < 93) {
    int idx = (bx - 13) * 256 + tid;            // < 20480  W2te[m][d][kf], f=64+kf
    int m = idx >> 12, d = (idx >> 6) & 63, kf = idx & 63;
    W2te[idx] = (f16)egw[(size_t)((64 + kf) * MM + m) * DD + d];
  } else {
    int idx = (bx - 93) * 256 + tid;            // < 40960  W2td[m][d][kf], f=kf
    int m = idx >> 13, d = (idx >> 7) & 63, kf = idx & 127;
    W2td[idx] = (f16)dgw[(size_t)(kf * MM + m) * DD + d];
  }
}

// recompute all 6 dots with decoder att_w at phase transition
__global__ __launch_bounds__(256) void k_trans(const float* __restrict__ hx,
                                               const float* __restrict__ daw,
                                               float* __restrict__ dots) {
  int p = blockIdx.x, b = blockIdx.y, tid = threadIdx.x;
  const float* h = hx + ((size_t)p * BB + b) * NN * DD;
  float s = 0.f;
  for (int i = tid; i < NN * DD; i += 256) s += h[i] * daw[i];
  __shared__ float red[256];
  red[tid] = s; __syncthreads();
  for (int st = 128; st; st >>= 1) { if (tid < st) red[tid] += red[tid + st]; __syncthreads(); }
  if (tid == 0) dots[b * 6 + p] = red[0];
}

// ---------------- z projection GEMM ----------------
// out z_m[(b*64+d)][n] = sum_f x[b,n,f] * W_m[f][d] ; enc: f in [64,128) + rank1 input term
__global__ __launch_bounds__(256) void k_z(
    int phase, int t,
    const f16* __restrict__ eo_in, const f16* __restrict__ h16,
    const f16* __restrict__ W2t,  const float* __restrict__ hist,
    const float* __restrict__ uv,
    const float* __restrict__ dots, const float* __restrict__ rdot,
    float* __restrict__ wbuf,
    float* __restrict__ z0f, float* __restrict__ z2f, float* __restrict__ z4f,
    f16* __restrict__ z1h, f16* __restrict__ z2h,
    f16* __restrict__ z3h, f16* __restrict__ z4h) {
  int tid = threadIdx.x;
  int m = blockIdx.y;
  int br = blockIdx.x * 128;
  const int K = phase ? 128 : 64;

  // fold per-step softmax over 6 attention scores into block (0,0)
  if (blockIdx.x == 0 && m == 0 && tid < BB) {
    float sc[6]; float mx = -1e30f;
    #pragma unroll
    for (int k = 0; k < 6; k++) { sc[k] = dots[tid * 6 + (t + k) % 6] + rdot[phase * 6 + k]; mx = fmaxf(mx, sc[k]); }
    float se = 0.f;
    #pragma unroll
    for (int k = 0; k < 6; k++) { sc[k] = __expf(sc[k] - mx); se += sc[k]; }
    float inv = 1.f / se;
    #pragma unroll
    for (int k = 0; k < 6; k++) wbuf[tid * 6 + k] = sc[k] * inv;
  }

  __shared__ f16 lA[128 * 128];
  __shared__ f16 lB[64 * 128];
  if (phase) {
    for (int idx = tid; idx < 128 * 16; idx += 256) {
      int row = idx >> 4, c8 = idx & 15;
      size_t go = (size_t)(br + row) * 64 + (size_t)(c8 & 7) * 8;
      const f16* src = (c8 < 8) ? (eo_in + go) : (h16 + go);
      *(f16x8*)&lA[row * 128 + c8 * 8] = *(const f16x8*)src;
    }
    for (int idx = tid; idx < 64 * 16; idx += 256) {
      int row = idx >> 4, c8 = idx & 15;
      *(f16x8*)&lB[row * 128 + c8 * 8] = *(const f16x8*)(W2t + ((size_t)m * 64 + row) * 128 + c8 * 8);
    }
  } else {
    for (int idx = tid; idx < 128 * 8; idx += 256) {
      int row = idx >> 3, c8 = idx & 7;
      *(f16x8*)&lA[row * 64 + c8 * 8] = *(const f16x8*)(h16 + (size_t)(br + row) * 64 + c8 * 8);
    }
    for (int idx = tid; idx < 64 * 8; idx += 256) {
      int row = idx >> 3, c8 = idx & 7;
      *(f16x8*)&lB[row * 64 + c8 * 8] = *(const f16x8*)(W2t + ((size_t)m * 64 + row) * 64 + c8 * 8);
    }
  }
  __syncthreads();

  int lane = tid & 63, w = tid >> 6;
  int wr = (w >> 1) * 64, wc = (w & 1) * 32;
  int l15 = lane & 15, k8 = (lane >> 4) * 8;
  f32x4 acc[4][2] = {};
  for (int ks = 0; ks < K; ks += 32) {
    f16x8 af[4], bf[2];
    #pragma unroll
    for (int fr = 0; fr < 4; fr++) af[fr] = *(const f16x8*)&lA[(wr + fr * 16 + l15) * K + ks + k8];
    #pragma unroll
    for (int fc = 0; fc < 2; fc++) bf[fc] = *(const f16x8*)&lB[(wc + fc * 16 + l15) * K + ks + k8];
    #pragma unroll
    for (int fr = 0; fr < 4; fr++)
      #pragma unroll
      for (int fc = 0; fc < 2; fc++)
        acc[fr][fc] = __builtin_amdgcn_mfma_f32_16x16x32_f16(af[fr], bf[fc], acc[fr][fc], 0, 0, 0);
  }

  int b = br / NP;
  int nb = br % NP;
  #pragma unroll
  for (int fr = 0; fr < 4; fr++)
    #pragma unroll
    for (int fc = 0; fc < 2; fc++) {
      int n = nb + wr + fr * 16 + (lane >> 4) * 4;
      int d = wc + fc * 16 + l15;
      f32x4 v = acc[fr][fc];
      if (phase == 0) {
        float uu = uv[m * 64 + d], vv = uv[320 + m * 64 + d];
        #pragma unroll
        for (int r = 0; r < 4; r++) {
          int nn_ = n + r;
          if (nn_ < NN) v[r] += hist[((size_t)b * LL + t) * NN + nn_] * uu + vv;
        }
      }
      size_t cb = (size_t)(b * 64 + d) * NP + n;
      f16x4 hv;
      #pragma unroll
      for (int r = 0; r < 4; r++) hv[r] = (f16)v[r];
      switch (m) {
        case 0: *(f32x4*)&z0f[cb] = v; break;
        case 1: *(f16x4*)&z1h[cb] = hv; break;
        case 2: *(f32x4*)&z2f[cb] = v; *(f16x4*)&z2h[cb] = hv; break;
        case 3: *(f16x4*)&z3h[cb] = hv; break;
        default: *(f32x4*)&z4f[cb] = v; *(f16x4*)&z4h[cb] = hv; break;
      }
    }
}

// ---------------- stage 1: a = S1 z2, c = S2 z4 ; writes comb = f16(z1+2a | z3+2c) ----------------
__global__ __launch_bounds__(256) void k_s1(
    int t, const f16* __restrict__ S12,
    const f16* __restrict__ z2h, const f16* __restrict__ z4h,
    const f16* __restrict__ z1h, const f16* __restrict__ z3h,
    f16* __restrict__ comb, float* __restrict__ dots) {
  int chain = blockIdx.z;
  const f16* Bt = chain ? z4h : z2h;
  const f16* zc = chain ? z3h : z1h;
  int br = blockIdx.x * 128, c0 = blockIdx.y * 128;
  int tid = threadIdx.x;
  if (blockIdx.x == 0 && blockIdx.y == 0 && chain == 0 && tid < BB) dots[tid * 6 + t % 6] = 0.f;

  __shared__ f16 lA[128 * 32], lB[128 * 32];
  int lane = tid & 63, w = tid >> 6;
  int wr = (w >> 1) * 64, wc = (w & 1) * 64;
  int l15 = lane & 15, k8 = (lane >> 4) * 8;
  f32x4 acc[4][4] = {};
  for (int ks = 0; ks < NP; ks += 32) {
    __syncthreads();
    #pragma unroll
    for (int j = 0; j < 2; j++) {
      int idx = tid + j * 256;
      int row = idx >> 2, c8 = idx & 3;
      *(f16x8*)&lA[row * 32 + c8 * 8] = *(const f16x8*)(S12 + (size_t)(br + row) * K2LEN + chain * NP + ks + c8 * 8);
      *(f16x8*)&lB[row * 32 + c8 * 8] = *(const f16x8*)(Bt + (size_t)(c0 + row) * NP + ks + c8 * 8);
    }
    __syncthreads();
    f16x8 af[4], bf[4];
    #pragma unroll
    for (int fr = 0; fr < 4; fr++) af[fr] = *(const f16x8*)&lA[(wr + fr * 16 + l15) * 32 + k8];
    #pragma unroll
    for (int fc = 0; fc < 4; fc++) bf[fc] = *(const f16x8*)&lB[(wc + fc * 16 + l15) * 32 + k8];
    #pragma unroll
    for (int fr = 0; fr < 4; fr++)
      #pragma unroll
      for (int fc = 0; fc < 4; fc++)
        acc[fr][fc] = __builtin_amdgcn_mfma_f32_16x16x32_f16(af[fr], bf[fc], acc[fr][fc], 0, 0, 0);
  }
  #pragma unroll
  for (int fr = 0; fr < 4; fr++)
    #pragma unroll
    for (int fc = 0; fc < 4; fc++) {
      int mm = br + wr + fr * 16 + (lane >> 4) * 4;
      int c  = c0 + wc + fc * 16 + l15;
      f16x4 zv = *(const f16x4*)&zc[(size_t)c * NP + mm];
      f16x4 o;
      #pragma unroll
      for (int r = 0; r < 4; r++) o[r] = (f16)((float)zv[r] + 2.f * acc[fr][fc][r]);
      *(f16x4*)&comb[(size_t)c * K2LEN + chain * NP + mm] = o;
    }
}

// ---------------- stage 2: bd[half] = S_half @ comb_half (k-split over the two chains) ----------------
__global__ __launch_bounds__(256) void k_s2(
    const f16* __restrict__ S12, const f16* __restrict__ comb, float* __restrict__ bd) {
  int half = blockIdx.z;
  int br = blockIdx.x * 128, c0 = blockIdx.y * 128;
  int tid = threadIdx.x;
  __shared__ f16 lA[128 * 32], lB[128 * 32];
  int lane = tid & 63, w = tid >> 6;
  int wr = (w >> 1) * 64, wc = (w & 1) * 64;
  int l15 = lane & 15, k8 = (lane >> 4) * 8;
  f32x4 acc[4][4] = {};
  for (int ks = 0; ks < NP; ks += 32) {
    __syncthreads();
    #pragma unroll
    for (int j = 0; j < 2; j++) {
      int idx = tid + j * 256;
      int row = idx >> 2, c8 = idx & 3;
      *(f16x8*)&lA[row * 32 + c8 * 8] = *(const f16x8*)(S12 + (size_t)(br + row) * K2LEN + half * NP + ks + c8 * 8);
      *(f16x8*)&lB[row * 32 + c8 * 8] = *(const f16x8*)(comb + (size_t)(c0 + row) * K2LEN + half * NP + ks + c8 * 8);
    }
    __syncthreads();
    f16x8 af[4], bf[4];
    #pragma unroll
    for (int fr = 0; fr < 4; fr++) af[fr] = *(const f16x8*)&lA[(wr + fr * 16 + l15) * 32 + k8];
    #pragma unroll
    for (int fc = 0; fc < 4; fc++) bf[fc] = *(const f16x8*)&lB[(wc + fc * 16 + l15) * 32 + k8];
    #pragma unroll
    for (int fr = 0; fr < 4; fr++)
      #pragma unroll
      for (int fc = 0; fc < 4; fc++)
        acc[fr][fc] = __builtin_amdgcn_mfma_f32_16x16x32_f16(af[fr], bf[fc], acc[fr][fc], 0, 0, 0);
  }
  #pragma unroll
  for (int fr = 0; fr < 4; fr++)
    #pragma unroll
    for (int fc = 0; fc < 4; fc++) {
      int mm = br + wr + fr * 16 + (lane >> 4) * 4;
      int c  = c0 + wc + fc * 16 + l15;
      *(f32x4*)&bd[((size_t)half * BD + c) * NP + mm] = acc[fr][fc];
    }
}

// ---------------- cell finish: conv, output, attention, ring write, dot-update, proj ----------------
__global__ __launch_bounds__(256) void k_fin(
    int phase, int t,
    const float* __restrict__ bd,  const float* __restrict__ z0f,
    const float* __restrict__ z2f, const float* __restrict__ z4f,
    const float* __restrict__ gb,  float* __restrict__ hx,
    const float* __restrict__ R,   const float* __restrict__ aW,
    const float* __restrict__ wbuf, float* __restrict__ dots,
    f16* __restrict__ h16, f16* __restrict__ eo_out,
    float* __restrict__ dout, const float* __restrict__ pw, const float* __restrict__ pbp) {
  int b = blockIdx.y, n0 = blockIdx.x * 64;
  int tid = threadIdx.x, lane = tid & 63, grp = tid >> 6;
  __shared__ float ls[64][65];
  int n_a = n0 + lane;
  #pragma unroll
  for (int i = 0; i < 16; i++) {
    int d = grp + 4 * i;
    size_t idx = (size_t)(b * 64 + d) * NP + n_a;
    float s = bd[idx] + bd[(size_t)BD * NP + idx] + z0f[idx] - z2f[idx] - z4f[idx] + gb[d];
    ls[lane][d] = s;
  }
  __syncthreads();
  int slotW = t % 6;
  float wk[6];
  int pidx[6];
  #pragma unroll
  for (int k = 0; k < 6; k++) { wk[k] = wbuf[b * 6 + k]; pidx[k] = (t + k) % 6; }
  const size_t plane = (size_t)BB * NN * DD;
  float pbv = pbp[0];
  float dsum = 0.f;
  for (int i = 0; i < 16; i++) {
    int nn_ = grp + 4 * i, n = n0 + nn_;
    if (n >= NN) continue;               // uniform across the wave
    int d = lane;
    float conv = ls[nn_][d];
    conv = conv > 0.f ? conv : 0.01f * conv;
    size_t hbase = ((size_t)b * NN + n) * DD + d;
    size_t rbase = (size_t)n * DD + d;
    float att = 0.f, hx5r = 0.f;
    #pragma unroll
    for (int k = 0; k < 6; k++) {
      float hv = hx[pidx[k] * plane + hbase];
      float rv = R[(size_t)k * NN * DD + rbase];
      float s2 = hv + rv;
      att += wk[k] * s2;
      if (k == 5) hx5r = s2;
    }
    float outp = hx5r + conv;
    hx[slotW * plane + hbase] = outp;
    h16[((size_t)b * NP + n) * DD + d] = (f16)outp;
    float oc = outp + att;
    dsum += outp * aW[n * DD + d];
    if (phase == 0) {
      eo_out[((size_t)b * NP + n) * DD + d] = (f16)oc;
    } else {
      float pv = oc * pw[d];
      #pragma unroll
      for (int s = 32; s; s >>= 1) pv += __shfl_xor(pv, s);
      if (lane == 0) dout[((size_t)b * HH + (t - LL)) * NN + n] = pv + pbv;
    }
  }
  #pragma unroll
  for (int s = 32; s; s >>= 1) dsum += __shfl_xor(dsum, s);
  if (lane == 0) atomicAdd(&dots[b * 6 + slotW], dsum);
}

// ---------------- host ----------------
extern "C" void kernel_launch(void* const* d_in, const int* in_sizes, int n_in,
                              void* d_out, int out_size, void* d_ws, size_t ws_size,
                              hipStream_t stream) {
  (void)in_sizes; (void)n_in; (void)out_size; (void)ws_size;
  const float* hist = (const float*)d_in[0];
  const float* adj  = (const float*)d_in[1];
  const float* emw  = (const float*)d_in[2];
  const float* emb  = (const float*)d_in[3];
  const float* egw  = (const float*)d_in[4];
  const float* egb  = (const float*)d_in[5];
  const float* eR   = (const float*)d_in[6];
  const float* eaw  = (const float*)d_in[7];
  const float* dgw  = (const float*)d_in[9];
  const float* dgb  = (const float*)d_in[10];
  const float* dR   = (const float*)d_in[11];
  const float* daw  = (const float*)d_in[12];
  const float* pw   = (const float*)d_in[14];
  const float* pb   = (const float*)d_in[15];

  char* w = (char*)d_ws;
  size_t off = 0;
  auto take = [&](size_t bytes) { char* p = w + off; off = (off + bytes + 255) & ~(size_t)255; return p; };
  f16*   S12  = (f16*)  take(896ULL * 1792 * 2);
  float* invr = (float*)take(896 * 4);
  float* invc = (float*)take(896 * 4);
  f16*   W2te = (f16*)  take(5 * 64 * 64 * 2);
  f16*   W2td = (f16*)  take(5 * 64 * 128 * 2);
  float* uv   = (float*)take(640 * 4);
  float* rdot = (float*)take(256);
  float* dots = (float*)take(768);
  float* wbuf = (float*)take(768);
  float* hx   = (float*)take(6ULL * 32 * 883 * 64 * 4);
  f16*   h16  = (f16*)  take(32ULL * 896 * 64 * 2);
  f16*   eoh  = (f16*)  take(12ULL * 32 * 896 * 64 * 2);
  float* z0f  = (float*)take(2048ULL * 896 * 4);
  float* z2f  = (float*)take(2048ULL * 896 * 4);
  float* z4f  = (float*)take(2048ULL * 896 * 4);
  f16*   z1h  = (f16*)  take(2048ULL * 896 * 2);
  f16*   z2h  = (f16*)  take(2048ULL * 896 * 2);
  f16*   z3h  = (f16*)  take(2048ULL * 896 * 2);
  f16*   z4h  = (f16*)  take(2048ULL * 896 * 2);
  f16*   comb = (f16*)  take(2048ULL * 1792 * 2);
  float* bd   = (float*)take(2ULL * 2048 * 896 * 4);
  // total ws usage ~154 MB

  hipMemsetAsync(hx, 0, 6ULL * 32 * 883 * 64 * 4, stream);
  hipMemsetAsync(h16, 0, 32ULL * 896 * 64 * 2, stream);
  hipMemsetAsync(eoh, 0, 12ULL * 32 * 896 * 64 * 2, stream);
  hipMemsetAsync(dots, 0, 768, stream);

  k_colrow<<<dim3(NN + 4), 256, 0, stream>>>(adj, invr, invc);
  k_sfill<<<dim3(896, 7), 256, 0, stream>>>(adj, invr, invc, S12);
  k_wprep<<<dim3(253), 256, 0, stream>>>(egw, dgw, emw, emb, eR, dR, eaw, daw, W2te, W2td, uv, rdot);

  for (int t = 0; t < 24; t++) {
    int ph = (t < LL) ? 0 : 1;
    if (t == LL) k_trans<<<dim3(6, 32), 256, 0, stream>>>(hx, daw, dots);
    const f16* eo_in = ph ? (eoh + (size_t)(t - LL) * 32 * 896 * 64) : (const f16*)nullptr;
    k_z<<<dim3(224, 5), 256, 0, stream>>>(ph, t, eo_in, h16, ph ? W2td : W2te, hist, uv,
                                          dots, rdot, wbuf, z0f, z2f, z4f, z1h, z2h, z3h, z4h);
    k_s1<<<dim3(7, 16, 2), 256, 0, stream>>>(t, S12, z2h, z4h, z1h, z3h, comb, dots);
    k_s2<<<dim3(7, 16, 2), 256, 0, stream>>>(S12, comb, bd);
    k_fin<<<dim3(14, 32), 256, 0, stream>>>(ph, t, bd, z0f, z2f, z4f, ph ? dgb : egb, hx,
                                            ph ? dR : eR, ph ? daw : eaw, wbuf, dots, h16,
                                            eoh + (ph ? 0 : (size_t)t * 32 * 896 * 64),
                                            (float*)d_out, pw, pb);
  }
}

// Round 2
// 2130.694 us; speedup vs baseline: 1.3085x; 1.3085x over previous
//
#include <hip/hip_runtime.h>
#include <hip/hip_fp16.h>

#define NN 883
#define NP 896
#define DD 64
#define BB 32
#define LL 12
#define HH 12
#define MM 5
#define KBIG 3584          // 4*NP
#define ZSL (32*896*64)    // eoh slice elems

typedef _Float16 f16;
typedef _Float16 f16x4 __attribute__((ext_vector_type(4)));
typedef _Float16 f16x8 __attribute__((ext_vector_type(8)));
typedef float    f32x4 __attribute__((ext_vector_type(4)));

#define GLL16(G, L) __builtin_amdgcn_global_load_lds((const __attribute__((address_space(1))) void*)(G), (__attribute__((address_space(3))) void*)(L), 16, 0, 0)

// ---------- prep: row/col inverse sums (coalesced) ----------
__global__ __launch_bounds__(256) void k_sums(const float* __restrict__ A,
                                              float* __restrict__ invr,
                                              float* __restrict__ invc) {
  int bx = blockIdx.x, tid = threadIdx.x;
  if (bx < NN) {
    float s = 0.f;
    for (int i = tid; i < NN; i += 256) s += A[(size_t)bx * NN + i];
    __shared__ float red[256];
    red[tid] = s; __syncthreads();
    for (int st = 128; st; st >>= 1) { if (tid < st) red[tid] += red[tid + st]; __syncthreads(); }
    if (tid == 0) invr[bx] = 1.0f / red[0];
  } else {
    int cb = (bx - NN) * 64; int c = cb + (tid & 63); int g = tid >> 6;
    float s = 0.f;
    if (c < NN) for (int r = g; r < NN; r += 4) s += A[(size_t)r * NN + c];
    __shared__ float red2[4][64];
    red2[g][tid & 63] = s; __syncthreads();
    if (tid < 64 && (cb + tid) < NN)
      invc[cb + tid] = 1.0f / (red2[0][tid] + red2[1][tid] + red2[2][tid] + red2[3][tid]);
  }
}

// ---------- prep: fill Sbig blocks 0,2 + S1T,S2T via tiled transpose ----------
__global__ __launch_bounds__(256) void k_sprep2(const float* __restrict__ A,
                                                const float* __restrict__ invr,
                                                const float* __restrict__ invc,
                                                f16* __restrict__ Sbig,
                                                f16* __restrict__ S1T,
                                                f16* __restrict__ S2T) {
  int r0 = blockIdx.y * 64, c0 = blockIdx.x * 64;
  int tid = threadIdx.x, lane = tid & 63, g = tid >> 6;
  __shared__ float tl[64][65];
  for (int i = g; i < 64; i += 4) {
    int r = r0 + i, c = c0 + lane;
    tl[i][lane] = (r < NN && c < NN) ? A[(size_t)r * NN + c] : 0.f;
  }
  __syncthreads();
  for (int i = g; i < 64; i += 4) {
    float v = tl[i][lane];
    int r = r0 + i, c = c0 + lane;
    Sbig[(size_t)r * KBIG + 2 * NP + c] = (f16)(v * invc[c]);   // S2[m=r][k=c]
    S1T[(size_t)r * NP + c] = (f16)(v * invr[r]);               // S1T[n=r][k=c]
  }
  for (int i = g; i < 64; i += 4) {
    float v = tl[lane][i];                                      // = A[r0+lane][c0+i]
    int m = c0 + i, k = r0 + lane;
    Sbig[(size_t)m * KBIG + k] = (f16)(v * invr[k]);            // S1[m][k]=A[k][m]*invr[k]
    S2T[(size_t)m * NP + k] = (f16)(v * invc[m]);               // S2T[n=m][k]=A[k][n]*invc[n]
  }
}

// ---------- prep: Sbig blocks 1,3 = 2*S^2 (GEMM A.B^T) ----------
__global__ __launch_bounds__(256) void k_ssq(f16* __restrict__ Sbig,
                                             const f16* __restrict__ S1T,
                                             const f16* __restrict__ S2T) {
  int c = blockIdx.z;
  const f16* Bt = c ? S2T : S1T;
  size_t aOff = (size_t)c * 2 * NP;
  int br = blockIdx.x * 128, c0 = blockIdx.y * 128;
  int tid = threadIdx.x;
  __shared__ f16 lA[128 * 32], lB[128 * 32];
  int lane = tid & 63, w = tid >> 6;
  int wr = (w >> 1) * 64, wc = (w & 1) * 64;
  int l15 = lane & 15, k8 = (lane >> 4) * 8;
  f32x4 acc[4][4] = {};
  for (int ks = 0; ks < NP; ks += 32) {
    __syncthreads();
    #pragma unroll
    for (int j = 0; j < 2; j++) {
      int idx = tid + j * 256;
      int row = idx >> 2, c8 = idx & 3;
      *(f16x8*)&lA[row * 32 + c8 * 8] = *(const f16x8*)(Sbig + (size_t)(br + row) * KBIG + aOff + ks + c8 * 8);
      *(f16x8*)&lB[row * 32 + c8 * 8] = *(const f16x8*)(Bt + (size_t)(c0 + row) * NP + ks + c8 * 8);
    }
    __syncthreads();
    f16x8 af[4], bf[4];
    #pragma unroll
    for (int fr = 0; fr < 4; fr++) af[fr] = *(const f16x8*)&lA[(wr + fr * 16 + l15) * 32 + k8];
    #pragma unroll
    for (int fc = 0; fc < 4; fc++) bf[fc] = *(const f16x8*)&lB[(wc + fc * 16 + l15) * 32 + k8];
    #pragma unroll
    for (int fr = 0; fr < 4; fr++)
      #pragma unroll
      for (int fc = 0; fc < 4; fc++)
        acc[fr][fc] = __builtin_amdgcn_mfma_f32_16x16x32_f16(af[fr], bf[fc], acc[fr][fc], 0, 0, 0);
  }
  size_t cOff = (size_t)(2 * c + 1) * NP;
  #pragma unroll
  for (int fr = 0; fr < 4; fr++)
    #pragma unroll
    for (int fc = 0; fc < 4; fc++) {
      int mmb = br + wr + fr * 16 + (lane >> 4) * 4;
      int ncol = c0 + wc + fc * 16 + l15;
      #pragma unroll
      for (int r = 0; r < 4; r++)
        Sbig[(size_t)(mmb + r) * KBIG + cOff + ncol] = (f16)(2.0f * acc[fr][fc][r]);
    }
}

// ---------- prep: W reorg + rank1 + rdot ----------
__global__ __launch_bounds__(256) void k_wprep(
    const float* __restrict__ egw, const float* __restrict__ dgw,
    const float* __restrict__ emw, const float* __restrict__ emb,
    const float* __restrict__ eR,  const float* __restrict__ dR,
    const float* __restrict__ eaw, const float* __restrict__ daw,
    f16* __restrict__ W2te, f16* __restrict__ W2td,
    float* __restrict__ uv, float* __restrict__ rdot) {
  int bx = blockIdx.x, tid = threadIdx.x;
  if (bx < 12) {
    int ph = bx / 6, k = bx % 6;
    const float* R  = ph ? dR : eR;
    const float* aw = ph ? daw : eaw;
    const float* Rk = R + (size_t)k * NN * DD;
    float s = 0.f;
    for (int i = tid; i < NN * DD; i += 256) s += Rk[i] * aw[i];
    __shared__ float red[256];
    red[tid] = s; __syncthreads();
    for (int st = 128; st; st >>= 1) { if (tid < st) red[tid] += red[tid + st]; __syncthreads(); }
    if (tid == 0) rdot[ph * 6 + k] = red[0];
  } else if (bx == 12) {
    for (int i = tid; i < 320; i += 256) {
      int m = i / 64, d = i % 64;
      float u = 0.f, v = 0.f;
      for (int f = 0; f < 64; f++) {
        float w = egw[(size_t)(f * MM + m) * DD + d];
        u += emw[f] * w;
        v += emb[f] * w;
      }
      uv[i] = u; uv[320 + i] = v;
    }
  } else if (bx < 93) {
    int idx = (bx - 13) * 256 + tid;            // W2te[m][d][kf], f=64+kf
    int m = idx >> 12, d = (idx >> 6) & 63, kf = idx & 63;
    W2te[idx] = (f16)egw[(size_t)((64 + kf) * MM + m) * DD + d];
  } else {
    int idx = (bx - 93) * 256 + tid;            // W2td[m][d][kf], f=kf
    int m = idx >> 13, d = (idx >> 7) & 63, kf = idx & 127;
    W2td[idx] = (f16)dgw[(size_t)(kf * MM + m) * DD + d];
  }
}

// ---------- init: zcat(0), wf(0) from rank-1 encoder input ----------
__global__ __launch_bounds__(256) void k_z0(const float* __restrict__ hist,
                                            const float* __restrict__ uv,
                                            f16* __restrict__ zout,
                                            float* __restrict__ wfout) {
  int col = blockIdx.x;               // b*64+d
  int b = col >> 6, d = col & 63;
  float u[5], v[5];
  #pragma unroll
  for (int m = 0; m < 5; m++) { u[m] = uv[m * 64 + d]; v[m] = uv[320 + m * 64 + d]; }
  for (int n = threadIdx.x; n < NP; n += 256) {
    bool valid = n < NN;
    float hv = valid ? hist[(size_t)b * LL * NN + n] : 0.f;
    #pragma unroll
    for (int m = 1; m < 5; m++)
      zout[(size_t)col * KBIG + (m - 1) * NP + n] = valid ? (f16)(hv * u[m] + v[m]) : (f16)0.f;
    wfout[(size_t)col * NP + n] = valid ?
      ((hv * u[0] + v[0]) - (hv * u[2] + v[2]) - (hv * u[4] + v[4])) : 0.f;
  }
}

// ---------- transition: recompute score dots with decoder att_w ----------
__global__ __launch_bounds__(256) void k_trans(const float* __restrict__ hx,
                                               const float* __restrict__ daw,
                                               float* __restrict__ D) {
  int p = blockIdx.x, b = blockIdx.y, tid = threadIdx.x;
  const float* h = hx + ((size_t)p * BB + b) * NN * DD;
  float s = 0.f;
  for (int i = tid; i < NN * DD; i += 256) s += h[i] * daw[i];
  __shared__ float red[256];
  red[tid] = s; __syncthreads();
  for (int st = 128; st; st >>= 1) { if (tid < st) red[tid] += red[tid + st]; __syncthreads(); }
  if (tid == 0) D[(12 + p) * 32 + b] = red[0];
}

// ---------- the fused step kernel ----------
__global__ __launch_bounds__(256, 1) void k_step(
    int t, int phase, int zmode,
    const f16* __restrict__ Sbig, const f16* __restrict__ zin, f16* __restrict__ zout,
    const float* __restrict__ wfin, float* __restrict__ wfout,
    float* __restrict__ D, const float* __restrict__ rdot,
    const float* __restrict__ gb, float* __restrict__ hx,
    const float* __restrict__ R, const float* __restrict__ aW,
    const f16* __restrict__ eo_in, f16* __restrict__ eo_out,
    const f16* __restrict__ W2t, const float* __restrict__ uv,
    const float* __restrict__ hist, float* __restrict__ dout,
    const float* __restrict__ pw, const float* __restrict__ pb) {
  __shared__ __align__(16) char smem[65536];
  // layout: main loop: sA dbuf [0,32768), sB dbuf [32768,49152)
  // after loop: ls2e [0,16384), ls2h [16384,32768), ls f32 [32768,65536)
  char* sAc = smem;
  char* sBc = smem + 32768;
  char* ls2e = smem;
  char* ls2h = smem + 16384;
  float* lsf = (float*)(smem + 32768);

  int tid = threadIdx.x;
  int br = blockIdx.x * 128;
  int b  = blockIdx.y;
  int c0 = b * 64;
  int lane = tid & 63, w = tid >> 6;
  int l15 = lane & 15, l16 = lane >> 4, x7 = l15 & 7;
  int wr = (w >> 1) * 64, wc = (w & 1) * 32;
  int cs8 = ((lane & 7) ^ (lane >> 3)) * 8;   // swizzled 16B slot (f16 units)

  // softmax weights for this step (all threads redundantly)
  float wk[6];
  {
    float sc[6], mx = -1e30f;
    #pragma unroll
    for (int k = 0; k < 6; k++) { sc[k] = D[(t + k) * 32 + b] + rdot[phase * 6 + k]; mx = fmaxf(mx, sc[k]); }
    float se = 0.f;
    #pragma unroll
    for (int k = 0; k < 6; k++) { sc[k] = __expf(sc[k] - mx); se += sc[k]; }
    float inv = 1.f / se;
    #pragma unroll
    for (int k = 0; k < 6; k++) wk[k] = sc[k] * inv;
  }

  auto STAGE = [&](int it, int buf) {
    const int ks_ = it * 64;
    #pragma unroll
    for (int ch = 0; ch < 4; ch++) {
      int base = w * 32 + ch * 8;
      const f16* g = Sbig + (size_t)(br + base + (lane >> 3)) * KBIG + ks_ + cs8;
      GLL16(g, sAc + buf * 16384 + base * 128);
    }
    #pragma unroll
    for (int ch = 0; ch < 2; ch++) {
      int base = w * 16 + ch * 8;
      const f16* g = zin + (size_t)(c0 + base + (lane >> 3)) * KBIG + ks_ + cs8;
      GLL16(g, sBc + buf * 8192 + base * 128);
    }
  };

  f32x4 acc[4][2] = {};
  STAGE(0, 0);
  for (int it = 0; it < 56; ++it) {
    int cur = it & 1;
    if (it + 1 < 56) {
      STAGE(it + 1, cur ^ 1);
      asm volatile("s_waitcnt vmcnt(6)" ::: "memory");
    } else {
      asm volatile("s_waitcnt vmcnt(0)" ::: "memory");
    }
    __builtin_amdgcn_s_barrier();
    #pragma unroll
    for (int kk = 0; kk < 2; kk++) {
      int sw = kk * 4 + l16;
      f16x8 af[4], bf[2];
      #pragma unroll
      for (int fr = 0; fr < 4; fr++) {
        int row = wr + fr * 16 + l15;
        af[fr] = *(const f16x8*)(sAc + cur * 16384 + row * 128 + ((sw ^ x7) << 4));
      }
      #pragma unroll
      for (int fc = 0; fc < 2; fc++) {
        int row = wc + fc * 16 + l15;
        bf[fc] = *(const f16x8*)(sBc + cur * 8192 + row * 128 + ((sw ^ x7) << 4));
      }
      #pragma unroll
      for (int fr = 0; fr < 4; fr++)
        #pragma unroll
        for (int fc = 0; fc < 2; fc++)
          acc[fr][fc] = __builtin_amdgcn_mfma_f32_16x16x32_f16(af[fr], bf[fc], acc[fr][fc], 0, 0, 0);
    }
    __builtin_amdgcn_s_barrier();
  }

  // issue eo-tile DMA into ls2e (dec z) -- completes before z-phase (syncthreads drains)
  if (zmode == 2) {
    #pragma unroll
    for (int ch = 0; ch < 4; ch++) {
      int base = w * 32 + ch * 8;
      const f16* g = eo_in + ((size_t)b * NP + br + base + (lane >> 3)) * 64 + cs8;
      GLL16(g, ls2e + base * 128);
    }
  }

  // frag epilogue: s = acc + wf + gb -> swizzled ls
  {
    float gbv[2];
    #pragma unroll
    for (int fc = 0; fc < 2; fc++) gbv[fc] = gb[wc + fc * 16 + l15];
    #pragma unroll
    for (int fr = 0; fr < 4; fr++)
      #pragma unroll
      for (int fc = 0; fc < 2; fc++) {
        int n = wr + fr * 16 + l16 * 4;
        int d = wc + fc * 16 + l15;
        f32x4 wv = *(const f32x4*)&wfin[(size_t)(c0 + d) * NP + br + n];
        #pragma unroll
        for (int r = 0; r < 4; r++) {
          int nr = n + r;
          lsf[nr * 64 + (d ^ ((((unsigned)nr >> 2) & 3) << 3))] = acc[fr][fc][r] + wv[r] + gbv[fc];
        }
      }
  }
  __syncthreads();

  // cell finish: conv->outp, ring write, attention, proj/eoh, dots
  int slotW = t % 6;
  const size_t plane = (size_t)BB * NN * DD;
  float pbv = pb[0];
  float dsum = 0.f;
  for (int i = 0; i < 32; i++) {
    int n_l = w + 4 * i;
    int n = br + n_l;
    int d = lane;
    float conv = lsf[n_l * 64 + (d ^ ((((unsigned)n_l >> 2) & 3) << 3))];
    conv = conv > 0.f ? conv : 0.01f * conv;
    float outp = 0.f;
    if (n < NN) {
      size_t hbase = ((size_t)b * NN + n) * DD + d;
      float att = 0.f, hx5r = 0.f;
      #pragma unroll
      for (int k = 0; k < 6; k++) {
        float hv = (t + k >= 6) ? hx[(size_t)((t + k) % 6) * plane + hbase] : 0.f;
        float rv = R[(size_t)k * NN * DD + (size_t)n * DD + d];
        float s2 = hv + rv;
        att += wk[k] * s2;
        if (k == 5) hx5r = s2;
      }
      outp = hx5r + conv;
      hx[(size_t)slotW * plane + hbase] = outp;
      float oc = outp + att;
      dsum += outp * aW[(size_t)n * DD + d];
      if (!phase) {
        eo_out[((size_t)b * NP + n) * DD + d] = (f16)oc;
      } else {
        float pv = oc * pw[d];
        #pragma unroll
        for (int s = 32; s; s >>= 1) pv += __shfl_xor(pv, s);
        if (lane == 0) dout[((size_t)b * HH + (t - LL)) * NN + n] = pv + pbv;
      }
    }
    // swizzled f16 write of outp (zeros for padding rows)
    int byteoff = n_l * 128 + ((((d >> 3) ^ (n_l & 7))) << 4) + (d & 7) * 2;
    *(f16*)(ls2h + byteoff) = (f16)outp;
  }
  #pragma unroll
  for (int s = 32; s; s >>= 1) dsum += __shfl_xor(dsum, s);
  if (lane == 0) atomicAdd(&D[(6 + t) * 32 + b], dsum);
  __syncthreads();   // drains eo DMA too

  // z-GEMM for step t+1
  if (zmode) {
    const int ZKW = (zmode == 2) ? 128 : 64;
    const int kb = (zmode == 2) ? 64 : 0;
    float hv_[2][4];
    if (zmode == 1) {
      #pragma unroll
      for (int fa = 0; fa < 2; fa++)
        #pragma unroll
        for (int r = 0; r < 4; r++) {
          int n = br + w * 32 + fa * 16 + l16 * 4 + r;
          hv_[fa][r] = (n < NN) ? hist[((size_t)b * LL + (t + 1)) * NN + n] : 0.f;
        }
    }
    f32x4 wacc[2][4];
    #pragma unroll
    for (int m = 0; m < 5; m++) {
      f32x4 zacc[2][4] = {};
      if (zmode == 2) {
        #pragma unroll
        for (int kk = 0; kk < 2; kk++) {
          int sw = kk * 4 + l16;
          f16x8 af[2], bf[4];
          #pragma unroll
          for (int fa = 0; fa < 2; fa++) {
            int row = w * 32 + fa * 16 + l15;
            af[fa] = *(const f16x8*)(ls2e + row * 128 + ((sw ^ x7) << 4));
          }
          #pragma unroll
          for (int fb = 0; fb < 4; fb++)
            bf[fb] = *(const f16x8*)&W2t[(size_t)(m * 64 + fb * 16 + l15) * ZKW + kk * 32 + l16 * 8];
          #pragma unroll
          for (int fa = 0; fa < 2; fa++)
            #pragma unroll
            for (int fb = 0; fb < 4; fb++)
              zacc[fa][fb] = __builtin_amdgcn_mfma_f32_16x16x32_f16(af[fa], bf[fb], zacc[fa][fb], 0, 0, 0);
        }
      }
      #pragma unroll
      for (int kk = 0; kk < 2; kk++) {
        int sw = kk * 4 + l16;
        f16x8 af[2], bf[4];
        #pragma unroll
        for (int fa = 0; fa < 2; fa++) {
          int row = w * 32 + fa * 16 + l15;
          af[fa] = *(const f16x8*)(ls2h + row * 128 + ((sw ^ x7) << 4));
        }
        #pragma unroll
        for (int fb = 0; fb < 4; fb++)
          bf[fb] = *(const f16x8*)&W2t[(size_t)(m * 64 + fb * 16 + l15) * ZKW + kb + kk * 32 + l16 * 8];
        #pragma unroll
        for (int fa = 0; fa < 2; fa++)
          #pragma unroll
          for (int fb = 0; fb < 4; fb++)
            zacc[fa][fb] = __builtin_amdgcn_mfma_f32_16x16x32_f16(af[fa], bf[fb], zacc[fa][fb], 0, 0, 0);
      }
      if (zmode == 1) {
        #pragma unroll
        for (int fb = 0; fb < 4; fb++) {
          float u = uv[m * 64 + fb * 16 + l15];
          float v = uv[320 + m * 64 + fb * 16 + l15];
          #pragma unroll
          for (int fa = 0; fa < 2; fa++)
            #pragma unroll
            for (int r = 0; r < 4; r++)
              zacc[fa][fb][r] += hv_[fa][r] * u + v;
        }
      }
      if (m == 0) {
        #pragma unroll
        for (int fa = 0; fa < 2; fa++)
          #pragma unroll
          for (int fb = 0; fb < 4; fb++) wacc[fa][fb] = zacc[fa][fb];
      } else {
        if (m == 2 || m == 4) {
          #pragma unroll
          for (int fa = 0; fa < 2; fa++)
            #pragma unroll
            for (int fb = 0; fb < 4; fb++)
              #pragma unroll
              for (int r = 0; r < 4; r++) wacc[fa][fb][r] -= zacc[fa][fb][r];
        }
        #pragma unroll
        for (int fa = 0; fa < 2; fa++)
          #pragma unroll
          for (int fb = 0; fb < 4; fb++) {
            int n = br + w * 32 + fa * 16 + l16 * 4;
            int dq = fb * 16 + l15;
            f16x4 hv4;
            #pragma unroll
            for (int r = 0; r < 4; r++) hv4[r] = (f16)zacc[fa][fb][r];
            *(f16x4*)&zout[(size_t)(c0 + dq) * KBIG + (m - 1) * NP + n] = hv4;
          }
      }
    }
    #pragma unroll
    for (int fa = 0; fa < 2; fa++)
      #pragma unroll
      for (int fb = 0; fb < 4; fb++) {
        int n = br + w * 32 + fa * 16 + l16 * 4;
        int dq = fb * 16 + l15;
        *(f32x4*)&wfout[(size_t)(c0 + dq) * NP + n] = wacc[fa][fb];
      }
  }
}

// ---------------- host ----------------
extern "C" void kernel_launch(void* const* d_in, const int* in_sizes, int n_in,
                              void* d_out, int out_size, void* d_ws, size_t ws_size,
                              hipStream_t stream) {
  (void)in_sizes; (void)n_in; (void)out_size; (void)ws_size;
  const float* hist = (const float*)d_in[0];
  const float* adj  = (const float*)d_in[1];
  const float* emw  = (const float*)d_in[2];
  const float* emb  = (const float*)d_in[3];
  const float* egw  = (const float*)d_in[4];
  const float* egb  = (const float*)d_in[5];
  const float* eR   = (const float*)d_in[6];
  const float* eaw  = (const float*)d_in[7];
  const float* dgw  = (const float*)d_in[9];
  const float* dgb  = (const float*)d_in[10];
  const float* dR   = (const float*)d_in[11];
  const float* daw  = (const float*)d_in[12];
  const float* pw   = (const float*)d_in[14];
  const float* pb   = (const float*)d_in[15];

  char* wsp = (char*)d_ws;
  size_t off = 0;
  auto take = [&](size_t bytes) { char* p = wsp + off; off = (off + bytes + 255) & ~(size_t)255; return p; };
  f16*   Sbig = (f16*)  take((size_t)NP * KBIG * 2);
  f16*   S1T  = (f16*)  take((size_t)NP * NP * 2);
  f16*   S2T  = (f16*)  take((size_t)NP * NP * 2);
  float* invr = (float*)take(NP * 4);
  float* invc = (float*)take(NP * 4);
  f16*   W2te = (f16*)  take(5 * 64 * 64 * 2);
  f16*   W2td = (f16*)  take(5 * 64 * 128 * 2);
  float* uv   = (float*)take(640 * 4);
  float* rdot = (float*)take(256);
  float* D    = (float*)take(30 * 32 * 4);
  float* hx   = (float*)take(6ULL * BB * NN * DD * 4);
  f16*   eoh  = (f16*)  take(12ULL * ZSL * 2);
  f16*   zc0  = (f16*)  take(2048ULL * KBIG * 2);
  f16*   zc1  = (f16*)  take(2048ULL * KBIG * 2);
  float* wf0  = (float*)take(2048ULL * NP * 4);
  float* wf1  = (float*)take(2048ULL * NP * 4);

  hipMemsetAsync(D, 0, 30 * 32 * 4, stream);

  k_sums<<<dim3(NN + 14), 256, 0, stream>>>(adj, invr, invc);
  k_sprep2<<<dim3(14, 14), 256, 0, stream>>>(adj, invr, invc, Sbig, S1T, S2T);
  k_ssq<<<dim3(7, 7, 2), 256, 0, stream>>>(Sbig, S1T, S2T);
  k_wprep<<<dim3(253), 256, 0, stream>>>(egw, dgw, emw, emb, eR, dR, eaw, daw, W2te, W2td, uv, rdot);
  k_z0<<<dim3(2048), 256, 0, stream>>>(hist, uv, zc0, wf0);

  f16* zc[2] = {zc0, zc1};
  float* wf[2] = {wf0, wf1};
  for (int t = 0; t < 24; t++) {
    int ph = (t >= 12) ? 1 : 0;
    int zmode = (t == 23) ? 0 : ((t + 1 >= 12) ? 2 : 1);
    if (t == 12) k_trans<<<dim3(6, 32), 256, 0, stream>>>(hx, daw, D);
    const f16* eo_in = (zmode == 2) ? (eoh + (size_t)(t + 1 - 12) * ZSL) : eoh;
    f16* eo_out = ph ? eoh : (eoh + (size_t)t * ZSL);
    const f16* Wz = (t + 1 < 12) ? W2te : W2td;
    k_step<<<dim3(7, 32), 256, 0, stream>>>(
        t, ph, zmode,
        Sbig, zc[t & 1], zc[(t + 1) & 1], wf[t & 1], wf[(t + 1) & 1],
        D, rdot, ph ? dgb : egb, hx, ph ? dR : eR, ph ? daw : eaw,
        eo_in, eo_out, Wz, uv, hist, (float*)d_out, pw, pb);
  }
}

// Round 3
// 2086.504 us; speedup vs baseline: 1.3362x; 1.0212x over previous
//
#include <hip/hip_runtime.h>
#include <hip/hip_fp16.h>

#define NN 883
#define NP 896
#define DD 64
#define BB 32
#define LL 12
#define HH 12
#define MM 5
#define KBIG 3584          // 4*NP
#define ZSL (32*896*64)    // eoh slice elems

typedef _Float16 f16;
typedef _Float16 f16x4 __attribute__((ext_vector_type(4)));
typedef _Float16 f16x8 __attribute__((ext_vector_type(8)));
typedef float    f32x4 __attribute__((ext_vector_type(4)));

#define GLL16(G, L) __builtin_amdgcn_global_load_lds((const __attribute__((address_space(1))) void*)(G), (__attribute__((address_space(3))) void*)(L), 16, 0, 0)

// ---------- prep: row/col inverse sums ----------
__global__ __launch_bounds__(256) void k_sums(const float* __restrict__ A,
                                              float* __restrict__ invr,
                                              float* __restrict__ invc) {
  int bx = blockIdx.x, tid = threadIdx.x, lane = tid & 63, w = tid >> 6;
  if (bx < 221) {
    int row = bx * 4 + w;
    float s = 0.f;
    if (row < NN) for (int i = lane; i < NN; i += 64) s += A[(size_t)row * NN + i];
    #pragma unroll
    for (int st = 32; st; st >>= 1) s += __shfl_xor(s, st);
    if (lane == 0 && row < NN) invr[row] = 1.0f / s;
  } else {
    int cb = (bx - 221) * 64; int c = cb + lane; int g = w;
    float s = 0.f;
    if (c < NN) for (int r = g; r < NN; r += 4) s += A[(size_t)r * NN + c];
    __shared__ float red2[4][64];
    red2[g][lane] = s; __syncthreads();
    if (tid < 64 && (cb + tid) < NN)
      invc[cb + tid] = 1.0f / (red2[0][tid] + red2[1][tid] + red2[2][tid] + red2[3][tid]);
  }
}

// ---------- prep: Sbig blocks 0,2 + S1T,S2T ----------
__global__ __launch_bounds__(256) void k_sprep2(const float* __restrict__ A,
                                                const float* __restrict__ invr,
                                                const float* __restrict__ invc,
                                                f16* __restrict__ Sbig,
                                                f16* __restrict__ S1T,
                                                f16* __restrict__ S2T) {
  int r0 = blockIdx.y * 64, c0 = blockIdx.x * 64;
  int tid = threadIdx.x, lane = tid & 63, g = tid >> 6;
  __shared__ float tl[64][65];
  for (int i = g; i < 64; i += 4) {
    int r = r0 + i, c = c0 + lane;
    tl[i][lane] = (r < NN && c < NN) ? A[(size_t)r * NN + c] : 0.f;
  }
  __syncthreads();
  for (int i = g; i < 64; i += 4) {
    float v = tl[i][lane];
    int r = r0 + i, c = c0 + lane;
    Sbig[(size_t)r * KBIG + 2 * NP + c] = (f16)(v * invc[c]);   // S2[m=r][k=c]
    S1T[(size_t)r * NP + c] = (f16)(v * invr[r]);
  }
  for (int i = g; i < 64; i += 4) {
    float v = tl[lane][i];                                      // = A[r0+lane][c0+i]
    int m = c0 + i, k = r0 + lane;
    Sbig[(size_t)m * KBIG + k] = (f16)(v * invr[k]);            // S1
    S2T[(size_t)m * NP + k] = (f16)(v * invc[m]);
  }
}

// ---------- prep: Sbig blocks 1,3 = 2*S^2 ----------
__global__ __launch_bounds__(256) void k_ssq(f16* __restrict__ Sbig,
                                             const f16* __restrict__ S1T,
                                             const f16* __restrict__ S2T) {
  int c = blockIdx.z;
  const f16* Bt = c ? S2T : S1T;
  size_t aOff = (size_t)c * 2 * NP;
  int br = blockIdx.x * 128, c0 = blockIdx.y * 128;
  int tid = threadIdx.x;
  __shared__ f16 lA[128 * 32], lB[128 * 32];
  int lane = tid & 63, w = tid >> 6;
  int wr = (w >> 1) * 64, wc = (w & 1) * 64;
  int l15 = lane & 15, k8 = (lane >> 4) * 8;
  f32x4 acc[4][4] = {};
  for (int ks = 0; ks < NP; ks += 32) {
    __syncthreads();
    #pragma unroll
    for (int j = 0; j < 2; j++) {
      int idx = tid + j * 256;
      int row = idx >> 2, c8 = idx & 3;
      *(f16x8*)&lA[row * 32 + c8 * 8] = *(const f16x8*)(Sbig + (size_t)(br + row) * KBIG + aOff + ks + c8 * 8);
      *(f16x8*)&lB[row * 32 + c8 * 8] = *(const f16x8*)(Bt + (size_t)(c0 + row) * NP + ks + c8 * 8);
    }
    __syncthreads();
    f16x8 af[4], bf[4];
    #pragma unroll
    for (int fr = 0; fr < 4; fr++) af[fr] = *(const f16x8*)&lA[(wr + fr * 16 + l15) * 32 + k8];
    #pragma unroll
    for (int fc = 0; fc < 4; fc++) bf[fc] = *(const f16x8*)&lB[(wc + fc * 16 + l15) * 32 + k8];
    #pragma unroll
    for (int fr = 0; fr < 4; fr++)
      #pragma unroll
      for (int fc = 0; fc < 4; fc++)
        acc[fr][fc] = __builtin_amdgcn_mfma_f32_16x16x32_f16(af[fr], bf[fc], acc[fr][fc], 0, 0, 0);
  }
  size_t cOff = (size_t)(2 * c + 1) * NP;
  #pragma unroll
  for (int fr = 0; fr < 4; fr++)
    #pragma unroll
    for (int fc = 0; fc < 4; fc++) {
      int mmb = br + wr + fr * 16 + (lane >> 4) * 4;
      int ncol = c0 + wc + fc * 16 + l15;
      #pragma unroll
      for (int r = 0; r < 4; r++)
        Sbig[(size_t)(mmb + r) * KBIG + cOff + ncol] = (f16)(2.0f * acc[fr][fc][r]);
    }
}

// ---------- prep: W reorg + rank1 + rdot (rdot split x8, atomic) ----------
__global__ __launch_bounds__(256) void k_wprep(
    const float* __restrict__ egw, const float* __restrict__ dgw,
    const float* __restrict__ emw, const float* __restrict__ emb,
    const float* __restrict__ eR,  const float* __restrict__ dR,
    const float* __restrict__ eaw, const float* __restrict__ daw,
    f16* __restrict__ W2te, f16* __restrict__ W2td,
    float* __restrict__ uv, float* __restrict__ rdot) {
  int bx = blockIdx.x, tid = threadIdx.x;
  if (bx < 96) {
    int ph = bx / 48, k = (bx / 8) % 6, part = bx & 7;
    const float* R  = ph ? dR : eR;
    const float* aw = ph ? daw : eaw;
    const float* Rk = R + (size_t)k * NN * DD;
    int base = part * 7064;
    float s = 0.f;
    for (int i = base + tid; i < base + 7064; i += 256) s += Rk[i] * aw[i];
    __shared__ float red[256];
    red[tid] = s; __syncthreads();
    for (int st = 128; st; st >>= 1) { if (tid < st) red[tid] += red[tid + st]; __syncthreads(); }
    if (tid == 0) atomicAdd(&rdot[ph * 6 + k], red[0]);
  } else if (bx == 96) {
    for (int i = tid; i < 320; i += 256) {
      int m = i / 64, d = i % 64;
      float u = 0.f, v = 0.f;
      for (int f = 0; f < 64; f++) {
        float w = egw[(size_t)(f * MM + m) * DD + d];
        u += emw[f] * w;
        v += emb[f] * w;
      }
      uv[i] = u; uv[320 + i] = v;
    }
  } else if (bx < 177) {
    int idx = (bx - 97) * 256 + tid;            // W2te[m][d][kf], f=64+kf
    int m = idx >> 12, d = (idx >> 6) & 63, kf = idx & 63;
    W2te[idx] = (f16)egw[(size_t)((64 + kf) * MM + m) * DD + d];
  } else {
    int idx = (bx - 177) * 256 + tid;           // W2td[m][d][kf], f=kf
    int m = idx >> 13, d = (idx >> 7) & 63, kf = idx & 127;
    W2td[idx] = (f16)dgw[(size_t)(kf * MM + m) * DD + d];
  }
}

// ---------- init: zcat(0), wf(0) ----------
__global__ __launch_bounds__(256) void k_z0(const float* __restrict__ hist,
                                            const float* __restrict__ uv,
                                            f16* __restrict__ zout,
                                            float* __restrict__ wfout) {
  int col = blockIdx.x;               // b*64+d
  int b = col >> 6, d = col & 63;
  float u[5], v[5];
  #pragma unroll
  for (int m = 0; m < 5; m++) { u[m] = uv[m * 64 + d]; v[m] = uv[320 + m * 64 + d]; }
  for (int n = threadIdx.x; n < NP; n += 256) {
    bool valid = n < NN;
    float hv = valid ? hist[(size_t)b * LL * NN + n] : 0.f;
    #pragma unroll
    for (int m = 1; m < 5; m++)
      zout[(size_t)col * KBIG + (m - 1) * NP + n] = valid ? (f16)(hv * u[m] + v[m]) : (f16)0.f;
    wfout[(size_t)col * NP + n] = valid ?
      ((hv * u[0] + v[0]) - (hv * u[2] + v[2]) - (hv * u[4] + v[4])) : 0.f;
  }
}

// ---------- transition: recompute score dots with decoder att_w (split x4, atomic) ----------
__global__ __launch_bounds__(256) void k_trans(const f16* __restrict__ hxh,
                                               const float* __restrict__ daw,
                                               float* __restrict__ D) {
  int p = blockIdx.x, b = blockIdx.y, q = blockIdx.z, tid = threadIdx.x;
  const f16* h = hxh + ((size_t)p * BB + b) * NN * DD;
  int base = q * 14128;
  float s = 0.f;
  for (int i = base + tid; i < base + 14128; i += 256) s += (float)h[i] * daw[i];
  __shared__ float red[256];
  red[tid] = s; __syncthreads();
  for (int st = 128; st; st >>= 1) { if (tid < st) red[tid] += red[tid + st]; __syncthreads(); }
  if (tid == 0) atomicAdd(&D[(12 + p) * 32 + b], red[0]);
}

// ---------- K1: main diffusion GEMM, K-split x2, 448 blocks ----------
__global__ __launch_bounds__(256, 2) void k_gemm(
    const f16* __restrict__ Sbig, const f16* __restrict__ zin,
    f16* __restrict__ bdh) {
  __shared__ __align__(16) char smem[49152];   // sA dbuf 2x16KB | sB dbuf 2x8KB
  char* sAc = smem;
  char* sBc = smem + 32768;
  int flat = blockIdx.x;
  int xcd = flat & 7, j = flat >> 3;
  int G = xcd * 56 + j;                         // b-major XCD grouping (bijective)
  int b = G / 14, rem = G % 14;
  int kc = rem / 7, br = (rem % 7) * 128;
  const int kbase = kc * 1792;
  int tid = threadIdx.x, lane = tid & 63, w = tid >> 6;
  int l15 = lane & 15, l16 = lane >> 4, x7 = l15 & 7;
  int wr = (w >> 1) * 64, wc = (w & 1) * 32;
  int srow = lane >> 3;
  int sslot = (lane & 7) ^ (srow & 7);          // pre-swizzled source slot

  auto STAGE = [&](int it, int buf) {
    const f16* gA = Sbig + (size_t)br * KBIG + kbase + it * 64;
    #pragma unroll
    for (int o = 0; o < 4; o++) {
      int rg = (w * 4 + o) * 8;
      GLL16(gA + (size_t)(rg + srow) * KBIG + sslot * 8, sAc + buf * 16384 + rg * 128);
    }
    const f16* gB = zin + (size_t)(b * 64) * KBIG + kbase + it * 64;
    #pragma unroll
    for (int o = 0; o < 2; o++) {
      int rg = (w * 2 + o) * 8;
      GLL16(gB + (size_t)(rg + srow) * KBIG + sslot * 8, sBc + buf * 8192 + rg * 128);
    }
  };

  f32x4 acc[4][2] = {};
  STAGE(0, 0);
  for (int it = 0; it < 28; ++it) {
    int cur = it & 1;
    if (it + 1 < 28) {
      STAGE(it + 1, cur ^ 1);
      asm volatile("s_waitcnt vmcnt(6)" ::: "memory");
    } else {
      asm volatile("s_waitcnt vmcnt(0)" ::: "memory");
    }
    __builtin_amdgcn_s_barrier();
    #pragma unroll
    for (int kk = 0; kk < 2; kk++) {
      int q = kk * 4 + l16;
      f16x8 af[4], bf[2];
      #pragma unroll
      for (int fr = 0; fr < 4; fr++) {
        int row = wr + fr * 16 + l15;
        af[fr] = *(const f16x8*)(sAc + cur * 16384 + row * 128 + ((q ^ x7) << 4));
      }
      #pragma unroll
      for (int fc = 0; fc < 2; fc++) {
        int row = wc + fc * 16 + l15;
        bf[fc] = *(const f16x8*)(sBc + cur * 8192 + row * 128 + ((q ^ x7) << 4));
      }
      #pragma unroll
      for (int fr = 0; fr < 4; fr++)
        #pragma unroll
        for (int fc = 0; fc < 2; fc++)
          acc[fr][fc] = __builtin_amdgcn_mfma_f32_16x16x32_f16(af[fr], bf[fc], acc[fr][fc], 0, 0, 0);
    }
    __builtin_amdgcn_s_barrier();
  }
  f16* out = bdh + (size_t)kc * ((size_t)2048 * NP);
  #pragma unroll
  for (int fr = 0; fr < 4; fr++)
    #pragma unroll
    for (int fc = 0; fc < 2; fc++) {
      int n = br + wr + fr * 16 + l16 * 4;
      int d = wc + fc * 16 + l15;
      f16x4 hv;
      #pragma unroll
      for (int r = 0; r < 4; r++) hv[r] = (f16)acc[fr][fc][r];
      *(f16x4*)&out[(size_t)(b * 64 + d) * NP + n] = hv;
    }
}

// ---------- K2: cell finish + fused z-GEMM for t+1, 448 blocks ----------
__global__ __launch_bounds__(256, 2) void k_fin(
    int t, int phase, int zmode,
    const f16* __restrict__ bdh, const float* __restrict__ wfin,
    const float* __restrict__ gb,
    float* __restrict__ D, const float* __restrict__ rdot,
    f16* __restrict__ hxh, float* __restrict__ prevf,
    const float* __restrict__ R, const float* __restrict__ aW,
    const f16* __restrict__ eo_in, f16* __restrict__ eo_out,
    const f16* __restrict__ W2t, const float* __restrict__ uv,
    const float* __restrict__ hist,
    f16* __restrict__ zout, float* __restrict__ wfout,
    float* __restrict__ dout, const float* __restrict__ pw, const float* __restrict__ pb) {
  __shared__ float lsf[64 * 64];   // conv-pre, transposed+swizzled
  __shared__ f16 ls2h[64 * 64];    // outp f16, swizzled for z-GEMM A-frags
  int flat = blockIdx.x;
  int xcd = flat & 7, jj = flat >> 3;
  int G = xcd * 56 + jj;
  int b = G / 14, nt = G % 14;
  int n0 = nt * 64, c0 = b * 64;
  int tid = threadIdx.x, lane = tid & 63, w = tid >> 6;
  int l15 = lane & 15, l16 = lane >> 4, x7 = l15 & 7;

  // softmax weights (redundant per thread)
  float wk[6];
  {
    float sc[6], mx = -1e30f;
    #pragma unroll
    for (int k = 0; k < 6; k++) { sc[k] = D[(t + k) * 32 + b] + rdot[phase * 6 + k]; mx = fmaxf(mx, sc[k]); }
    float se = 0.f;
    #pragma unroll
    for (int k = 0; k < 6; k++) { sc[k] = __expf(sc[k] - mx); se += sc[k]; }
    float inv = 1.f / se;
    #pragma unroll
    for (int k = 0; k < 6; k++) wk[k] = sc[k] * inv;
  }

  // phase A: conv-pre = bd0+bd1+wf+gb, transpose into lsf
  {
    int col = tid >> 2, ns = tid & 3;
    size_t base = (size_t)(c0 + col) * NP + n0 + ns * 16;
    f16x8 p0a = *(const f16x8*)&bdh[base];
    f16x8 p0b = *(const f16x8*)&bdh[base + 8];
    f16x8 p1a = *(const f16x8*)&bdh[(size_t)2048 * NP + base];
    f16x8 p1b = *(const f16x8*)&bdh[(size_t)2048 * NP + base + 8];
    float gbv = gb[col];
    #pragma unroll
    for (int jx = 0; jx < 16; jx++) {
      float s = ((jx < 8) ? ((float)p0a[jx] + (float)p1a[jx]) : ((float)p0b[jx - 8] + (float)p1b[jx - 8]))
              + wfin[base + jx] + gbv;
      int n_ = ns * 16 + jx;
      lsf[n_ * 64 + (col ^ (n_ & 7))] = s;
    }
  }
  __syncthreads();

  // phase B: cell finish
  int slotW = t % 6;
  const size_t plane = (size_t)BB * NN * DD;
  float pbv = pb[0];
  float dsum = 0.f;
  for (int i = 0; i < 16; i++) {
    int n_l = w + 4 * i;
    int n = n0 + n_l;
    int d = lane;
    float conv = lsf[n_l * 64 + (d ^ (n_l & 7))];
    conv = conv > 0.f ? conv : 0.01f * conv;
    float outp = 0.f;
    if (n < NN) {
      size_t hbase = ((size_t)b * NN + n) * DD + d;
      size_t rbase = (size_t)n * DD + d;
      float att = 0.f;
      #pragma unroll
      for (int k = 0; k < 5; k++) {
        float hv = (t + k >= 6) ? (float)hxh[(size_t)((t + k) % 6) * plane + hbase] : 0.f;
        att += wk[k] * (hv + R[(size_t)k * NN * DD + rbase]);
      }
      float hv5 = (t >= 1) ? prevf[hbase] : 0.f;
      float s5 = hv5 + R[(size_t)5 * NN * DD + rbase];
      att += wk[5] * s5;
      outp = s5 + conv;
      prevf[hbase] = outp;
      hxh[(size_t)slotW * plane + hbase] = (f16)outp;
      float oc = outp + att;
      dsum += outp * aW[rbase];
      if (!phase) {
        eo_out[((size_t)b * NP + n) * DD + d] = (f16)oc;
      } else {
        float pv = oc * pw[d];
        #pragma unroll
        for (int s = 32; s; s >>= 1) pv += __shfl_xor(pv, s);
        if (lane == 0) dout[((size_t)b * HH + (t - LL)) * NN + n] = pv + pbv;
      }
    }
    ls2h[n_l * 64 + (((d >> 3) ^ (n_l & 7)) << 3) + (d & 7)] = (f16)outp;
  }
  #pragma unroll
  for (int s = 32; s; s >>= 1) dsum += __shfl_xor(dsum, s);
  if (lane == 0) atomicAdd(&D[(6 + t) * 32 + b], dsum);
  __syncthreads();

  // phase C: z-GEMM for step t+1
  if (zmode) {
    const int ZKW = (zmode == 2) ? 128 : 64;
    const int kh32 = (zmode == 2) ? 2 : 0;   // h-features k-offset (in 32s)
    f16x8 afh[2];
    #pragma unroll
    for (int kk = 0; kk < 2; kk++) {
      int row = w * 16 + l15;
      int q = kk * 4 + l16;
      afh[kk] = *(const f16x8*)&ls2h[row * 64 + ((q ^ x7) << 3)];
    }
    f16x8 afe[2];
    if (zmode == 2) {
      #pragma unroll
      for (int kk = 0; kk < 2; kk++)
        afe[kk] = *(const f16x8*)&eo_in[((size_t)b * NP + n0 + w * 16 + l15) * 64 + kk * 32 + l16 * 8];
    }
    float hv_[4];
    if (zmode == 1) {
      #pragma unroll
      for (int r = 0; r < 4; r++) {
        int n = n0 + w * 16 + l16 * 4 + r;
        hv_[r] = (n < NN) ? hist[((size_t)b * LL + (t + 1)) * NN + n] : 0.f;
      }
    }
    f32x4 wacc[4];
    #pragma unroll
    for (int m = 0; m < 5; m++) {
      f32x4 zacc[4] = {};
      #pragma unroll
      for (int kk = 0; kk < 2; kk++)
        #pragma unroll
        for (int fb = 0; fb < 4; fb++) {
          f16x8 bfv = *(const f16x8*)&W2t[(size_t)(m * 64 + fb * 16 + l15) * ZKW + (kh32 + kk) * 32 + l16 * 8];
          zacc[fb] = __builtin_amdgcn_mfma_f32_16x16x32_f16(afh[kk], bfv, zacc[fb], 0, 0, 0);
        }
      if (zmode == 2) {
        #pragma unroll
        for (int kk = 0; kk < 2; kk++)
          #pragma unroll
          for (int fb = 0; fb < 4; fb++) {
            f16x8 bfv = *(const f16x8*)&W2t[(size_t)(m * 64 + fb * 16 + l15) * ZKW + kk * 32 + l16 * 8];
            zacc[fb] = __builtin_amdgcn_mfma_f32_16x16x32_f16(afe[kk], bfv, zacc[fb], 0, 0, 0);
          }
      }
      if (zmode == 1) {
        #pragma unroll
        for (int fb = 0; fb < 4; fb++) {
          float u = uv[m * 64 + fb * 16 + l15];
          float v = uv[320 + m * 64 + fb * 16 + l15];
          #pragma unroll
          for (int r = 0; r < 4; r++) zacc[fb][r] += hv_[r] * u + v;
        }
      }
      if (m == 0) {
        #pragma unroll
        for (int fb = 0; fb < 4; fb++) wacc[fb] = zacc[fb];
      } else {
        if (m == 2 || m == 4) {
          #pragma unroll
          for (int fb = 0; fb < 4; fb++)
            #pragma unroll
            for (int r = 0; r < 4; r++) wacc[fb][r] -= zacc[fb][r];
        }
        #pragma unroll
        for (int fb = 0; fb < 4; fb++) {
          int n = n0 + w * 16 + l16 * 4;
          int d = fb * 16 + l15;
          f16x4 hv4;
          #pragma unroll
          for (int r = 0; r < 4; r++) hv4[r] = (f16)zacc[fb][r];
          *(f16x4*)&zout[(size_t)(c0 + d) * KBIG + (m - 1) * NP + n] = hv4;
        }
      }
    }
    #pragma unroll
    for (int fb = 0; fb < 4; fb++) {
      int n = n0 + w * 16 + l16 * 4;
      int d = fb * 16 + l15;
      *(f32x4*)&wfout[(size_t)(c0 + d) * NP + n] = wacc[fb];
    }
  }
}

// ---------------- host ----------------
extern "C" void kernel_launch(void* const* d_in, const int* in_sizes, int n_in,
                              void* d_out, int out_size, void* d_ws, size_t ws_size,
                              hipStream_t stream) {
  (void)in_sizes; (void)n_in; (void)out_size; (void)ws_size;
  const float* hist = (const float*)d_in[0];
  const float* adj  = (const float*)d_in[1];
  const float* emw  = (const float*)d_in[2];
  const float* emb  = (const float*)d_in[3];
  const float* egw  = (const float*)d_in[4];
  const float* egb  = (const float*)d_in[5];
  const float* eR   = (const float*)d_in[6];
  const float* eaw  = (const float*)d_in[7];
  const float* dgw  = (const float*)d_in[9];
  const float* dgb  = (const float*)d_in[10];
  const float* dR   = (const float*)d_in[11];
  const float* daw  = (const float*)d_in[12];
  const float* pw   = (const float*)d_in[14];
  const float* pb   = (const float*)d_in[15];

  char* wsp = (char*)d_ws;
  size_t off = 0;
  auto take = [&](size_t bytes) { char* p = wsp + off; off = (off + bytes + 255) & ~(size_t)255; return p; };
  f16*   Sbig  = (f16*)  take((size_t)NP * KBIG * 2);
  f16*   S1T   = (f16*)  take((size_t)NP * NP * 2);
  f16*   S2T   = (f16*)  take((size_t)NP * NP * 2);
  float* invr  = (float*)take(NP * 4);
  float* invc  = (float*)take(NP * 4);
  f16*   W2te  = (f16*)  take(5 * 64 * 64 * 2);
  f16*   W2td  = (f16*)  take(5 * 64 * 128 * 2);
  float* uv    = (float*)take(640 * 4);
  float* rdot  = (float*)take(256);
  float* D     = (float*)take(30 * 32 * 4);
  f16*   hxh   = (f16*)  take(6ULL * BB * NN * DD * 2);
  float* prevf = (float*)take((size_t)BB * NN * DD * 4);
  f16*   eoh   = (f16*)  take(12ULL * ZSL * 2);
  f16*   zc0   = (f16*)  take(2048ULL * KBIG * 2);
  f16*   zc1   = (f16*)  take(2048ULL * KBIG * 2);
  float* wf0   = (float*)take(2048ULL * NP * 4);
  float* wf1   = (float*)take(2048ULL * NP * 4);
  f16*   bdh   = (f16*)  take(2ULL * 2048 * NP * 2);

  hipMemsetAsync(D, 0, 30 * 32 * 4, stream);
  hipMemsetAsync(rdot, 0, 256, stream);

  k_sums<<<dim3(235), 256, 0, stream>>>(adj, invr, invc);
  k_sprep2<<<dim3(14, 14), 256, 0, stream>>>(adj, invr, invc, Sbig, S1T, S2T);
  k_ssq<<<dim3(7, 7, 2), 256, 0, stream>>>(Sbig, S1T, S2T);
  k_wprep<<<dim3(337), 256, 0, stream>>>(egw, dgw, emw, emb, eR, dR, eaw, daw, W2te, W2td, uv, rdot);
  k_z0<<<dim3(2048), 256, 0, stream>>>(hist, uv, zc0, wf0);

  f16* zc[2] = {zc0, zc1};
  float* wf[2] = {wf0, wf1};
  for (int t = 0; t < 24; t++) {
    int ph = (t >= 12) ? 1 : 0;
    int zmode = (t == 23) ? 0 : ((t + 1 >= 12) ? 2 : 1);
    k_gemm<<<dim3(448), 256, 0, stream>>>(Sbig, zc[t & 1], bdh);
    if (t == 12) {
      hipMemsetAsync((char*)(D + 12 * 32), 0, 6 * 32 * 4, stream);
      k_trans<<<dim3(6, 32, 4), 256, 0, stream>>>(hxh, daw, D);
    }
    k_fin<<<dim3(448), 256, 0, stream>>>(
        t, ph, zmode, bdh, wf[t & 1], ph ? dgb : egb,
        D, rdot, hxh, prevf, ph ? dR : eR, ph ? daw : eaw,
        (zmode == 2) ? (eoh + (size_t)(t + 1 - 12) * ZSL) : eoh,
        ph ? eoh : (eoh + (size_t)t * ZSL),
        (t + 1 < 12) ? W2te : W2td, uv, hist,
        zc[(t + 1) & 1], wf[(t + 1) & 1], (float*)d_out, pw, pb);
  }
}